// Round 1
// baseline (70.662 us; speedup 1.0000x reference)
//
#include <hip/hip_runtime.h>

#define BB 16384
#define CC 10
#define KK 20
#define DD 128

__device__ __forceinline__ float log_sigmoid(float x) {
    // log sigma(x) = min(x,0) - log1p(exp(-|x|))  (numerically stable)
    return fminf(x, 0.0f) - log1pf(__expf(-fabsf(x)));
}

__global__ __launch_bounds__(256) void w2v_loss_kernel(
    const int*   __restrict__ context,   // [B, C]
    const int*   __restrict__ target,    // [B]
    const int*   __restrict__ negs,      // [B, K]
    const float* __restrict__ embW,      // [V, D]
    const float* __restrict__ ctxW,      // [V, D]
    float*       __restrict__ block_part // [gridDim.x]
) {
    const int wave = threadIdx.x >> 6;
    const int lane = threadIdx.x & 63;
    const int b = blockIdx.x * 4 + wave;   // grid = B/4, always in range

    const float2* ctxW2 = reinterpret_cast<const float2*>(ctxW);
    const float2* embW2 = reinterpret_cast<const float2*>(embW);

    // ---- context mean: each lane owns dims [2*lane, 2*lane+1] ----
    float2 acc = make_float2(0.f, 0.f);
    #pragma unroll
    for (int c = 0; c < CC; ++c) {
        const int idx = context[b * CC + c];
        const float2 v = ctxW2[(size_t)idx * (DD / 2) + lane];
        acc.x += v.x; acc.y += v.y;
    }
    acc.x *= (1.0f / CC);
    acc.y *= (1.0f / CC);

    // ---- target dot ----
    const int t = target[b];
    const float2 tv = embW2[(size_t)t * (DD / 2) + lane];
    float pd = acc.x * tv.x + acc.y * tv.y;

    // ---- negative dots: gather all partials first (ILP), reduce together ----
    float nd[KK];
    #pragma unroll
    for (int k = 0; k < KK; ++k) {
        const int n = negs[b * KK + k];
        const float2 nv = ctxW2[(size_t)n * (DD / 2) + lane];
        nd[k] = acc.x * nv.x + acc.y * nv.y;
    }

    #pragma unroll
    for (int off = 32; off; off >>= 1) {
        pd += __shfl_xor(pd, off, 64);
        #pragma unroll
        for (int k = 0; k < KK; ++k) nd[k] += __shfl_xor(nd[k], off, 64);
    }

    float score = log_sigmoid(pd);
    #pragma unroll
    for (int k = 0; k < KK; ++k) score += log_sigmoid(-nd[k]);

    // ---- per-block partial sum (4 waves) ----
    __shared__ float sp[4];
    if (lane == 0) sp[wave] = score;
    __syncthreads();
    if (threadIdx.x == 0)
        block_part[blockIdx.x] = sp[0] + sp[1] + sp[2] + sp[3];
}

__global__ __launch_bounds__(256) void w2v_finish_kernel(
    const float* __restrict__ part, float* __restrict__ out, int n, float scale)
{
    __shared__ float sm[4];
    float s = 0.f;
    for (int i = threadIdx.x; i < n; i += 256) s += part[i];
    #pragma unroll
    for (int off = 32; off; off >>= 1) s += __shfl_xor(s, off, 64);
    const int wave = threadIdx.x >> 6;
    const int lane = threadIdx.x & 63;
    if (lane == 0) sm[wave] = s;
    __syncthreads();
    if (threadIdx.x == 0) out[0] = (sm[0] + sm[1] + sm[2] + sm[3]) * scale;
}

extern "C" void kernel_launch(void* const* d_in, const int* in_sizes, int n_in,
                              void* d_out, int out_size, void* d_ws, size_t ws_size,
                              hipStream_t stream) {
    const int*   context = (const int*)d_in[0];
    const int*   target  = (const int*)d_in[1];
    const int*   negs    = (const int*)d_in[2];
    const float* embW    = (const float*)d_in[3];
    const float* ctxW    = (const float*)d_in[4];
    float* out = (float*)d_out;

    float* block_part = (float*)d_ws;          // 4096 floats = 16 KB scratch
    const int nblocks = BB / 4;                // 4096

    w2v_loss_kernel<<<nblocks, 256, 0, stream>>>(context, target, negs, embW, ctxW, block_part);
    w2v_finish_kernel<<<1, 256, 0, stream>>>(block_part, out, nblocks, -1.0f / (float)BB);
}

// Round 2
// 43.500 us; speedup vs baseline: 1.6244x; 1.6244x over previous
//
#include <hip/hip_runtime.h>

#define BB 16384
#define CC 10
#define KK 20
#define DD 128

// fast, accurate-enough log sigmoid: logsig(x) = min(x,0) - log(1 + exp(-|x|))
__device__ __forceinline__ float lsg(float x) {
    return fminf(x, 0.0f) - __logf(1.0f + __expf(-fabsf(x)));
}

// butterfly add via ds_swizzle (xor pattern, no address calc). MASK must be ICE.
template <int MASK>
__device__ __forceinline__ float swz_add(float v) {
    int r = __builtin_amdgcn_ds_swizzle(__float_as_int(v), MASK);
    return v + __int_as_float(r);
}

__device__ __forceinline__ float dot4(float4 a, float4 b) {
    return a.x * b.x + a.y * b.y + a.z * b.z + a.w * b.w;
}

__global__ __launch_bounds__(256) void w2v_loss_kernel(
    const int*   __restrict__ context,   // [B, C]
    const int*   __restrict__ target,    // [B]
    const int*   __restrict__ negs,      // [B, K]
    const float* __restrict__ embW,      // [V, D]
    const float* __restrict__ ctxW,      // [V, D]
    float*       __restrict__ block_part // [gridDim.x]
) {
    const int wave  = threadIdx.x >> 6;
    const int lane  = threadIdx.x & 63;
    const int group = lane >> 4;          // 4 groups of 16 lanes per wave
    const int gl    = lane & 15;

    // 16 b's per block: 4 waves x 4 groups
    const int b = blockIdx.x * 16 + wave * 4 + group;

    const float4* ctxW4 = reinterpret_cast<const float4*>(ctxW);
    const float4* embW4 = reinterpret_cast<const float4*>(embW);

    // each lane owns dims [4*gl .. 4*gl+3] and [64+4*gl .. 64+4*gl+3]
    const int* cbase = context + b * CC;
    const int* nbase = negs    + b * KK;

    // ---- context mean ----
    float4 accA = make_float4(0.f, 0.f, 0.f, 0.f);
    float4 accB = make_float4(0.f, 0.f, 0.f, 0.f);
    #pragma unroll
    for (int c = 0; c < CC; ++c) {
        const size_t row = (size_t)cbase[c] * (DD / 4);
        const float4 vA = ctxW4[row + gl];
        const float4 vB = ctxW4[row + 16 + gl];
        accA.x += vA.x; accA.y += vA.y; accA.z += vA.z; accA.w += vA.w;
        accB.x += vB.x; accB.y += vB.y; accB.z += vB.z; accB.w += vB.w;
    }
    const float inv = 1.0f / CC;
    accA.x *= inv; accA.y *= inv; accA.z *= inv; accA.w *= inv;
    accB.x *= inv; accB.y *= inv; accB.z *= inv; accB.w *= inv;

    // ---- target dot partial ----
    const size_t trow = (size_t)target[b] * (DD / 4);
    float pd = dot4(accA, embW4[trow + gl]) + dot4(accB, embW4[trow + 16 + gl]);

    // ---- negative dot partials ----
    float nd[KK];
    #pragma unroll
    for (int k = 0; k < KK; ++k) {
        const size_t row = (size_t)nbase[k] * (DD / 4);
        nd[k] = dot4(accA, ctxW4[row + gl]) + dot4(accB, ctxW4[row + 16 + gl]);
    }

    // ---- reduce over the 16 lanes of the group: xor 1,2,4,8 via ds_swizzle ----
    pd = swz_add<0x041F>(pd);
    #pragma unroll
    for (int k = 0; k < KK; ++k) nd[k] = swz_add<0x041F>(nd[k]);
    pd = swz_add<0x081F>(pd);
    #pragma unroll
    for (int k = 0; k < KK; ++k) nd[k] = swz_add<0x081F>(nd[k]);
    pd = swz_add<0x101F>(pd);
    #pragma unroll
    for (int k = 0; k < KK; ++k) nd[k] = swz_add<0x101F>(nd[k]);
    pd = swz_add<0x201F>(pd);
    #pragma unroll
    for (int k = 0; k < KK; ++k) nd[k] = swz_add<0x201F>(nd[k]);

    // ---- per-b score (computed once per wave for all 4 b's in parallel) ----
    float score = lsg(pd);
    #pragma unroll
    for (int k = 0; k < KK; ++k) score += lsg(-nd[k]);

    // ---- combine the 4 groups of this wave: xor 16 (swizzle) + xor 32 (shfl) ----
    float s = swz_add<0x401F>(score);
    s += __shfl_xor(s, 32, 64);

    __shared__ float sp[4];
    if (lane == 0) sp[wave] = s;
    __syncthreads();
    if (threadIdx.x == 0)
        block_part[blockIdx.x] = sp[0] + sp[1] + sp[2] + sp[3];
}

__global__ __launch_bounds__(256) void w2v_finish_kernel(
    const float* __restrict__ part, float* __restrict__ out, int n, float scale)
{
    __shared__ float sm[4];
    float s = 0.f;
    for (int i = threadIdx.x; i < n; i += 256) s += part[i];
    #pragma unroll
    for (int off = 32; off; off >>= 1) s += __shfl_xor(s, off, 64);
    const int wave = threadIdx.x >> 6;
    const int lane = threadIdx.x & 63;
    if (lane == 0) sm[wave] = s;
    __syncthreads();
    if (threadIdx.x == 0) out[0] = (sm[0] + sm[1] + sm[2] + sm[3]) * scale;
}

extern "C" void kernel_launch(void* const* d_in, const int* in_sizes, int n_in,
                              void* d_out, int out_size, void* d_ws, size_t ws_size,
                              hipStream_t stream) {
    const int*   context = (const int*)d_in[0];
    const int*   target  = (const int*)d_in[1];
    const int*   negs    = (const int*)d_in[2];
    const float* embW    = (const float*)d_in[3];
    const float* ctxW    = (const float*)d_in[4];
    float* out = (float*)d_out;

    float* block_part = (float*)d_ws;          // 1024 floats = 4 KB scratch
    const int nblocks = BB / 16;               // 1024 blocks x 16 b's

    w2v_loss_kernel<<<nblocks, 256, 0, stream>>>(context, target, negs, embW, ctxW, block_part);
    w2v_finish_kernel<<<1, 256, 0, stream>>>(block_part, out, nblocks, -1.0f / (float)BB);
}